// Round 4
// baseline (751.268 us; speedup 1.0000x reference)
//
#include <hip/hip_runtime.h>
#include <hip/hip_fp16.h>

#define TPB 256
#define STPB 512           // threads for scatter_sort
#define BTPB 1024          // threads for bucket_csr
#define NBK 256            // bucket index space (dst >> 12); 245 used
#define BNODES 4096        // nodes per bucket
#define CH 6144            // edges per scatter_sort chunk (34 KB LDS -> 4 blocks/CU)
#define CAPB 45056         // fixed bucket capacity (mean 40960 + 20 sigma)
#define CAP_L 262144       // cone row cap (|marked| ~ 92K mean)
#define HSTG 27648         // per-half LDS stage capacity (108 KB; mean 20480 + 50 sigma)

typedef unsigned int uv4 __attribute__((ext_vector_type(4)));
union H8 { uv4 u; __half2 h2[4]; };

// ---------------- init: tails[b] = b * CAPB ----------------
__global__ void init_tails(int* __restrict__ tails) {
    tails[threadIdx.x] = threadIdx.x * CAPB;
}

// ------- partition edges into fixed-capacity buckets; LDS counting sort, burst flush ---
// payload: (dstLow12 << 20) | src  (exactly 32 bits; requires n <= 2^20)
// Also piggybacks global in-degree atomics (fire-and-forget, rides latency slack).
__global__ __launch_bounds__(STPB) void scatter_sort(const int* __restrict__ dst,
                                                     const int* __restrict__ src,
                                                     int* __restrict__ tails,
                                                     int* __restrict__ deg,
                                                     unsigned* __restrict__ bdata, int nE) {
    __shared__ unsigned      stage[CH];      // 24 KB
    __shared__ unsigned char bkt[CH];        // 6 KB
    __shared__ int cnt[NBK], sstart[NBK], cur[NBK], cbase[NBK];   // 4 KB
    __shared__ int wsum[STPB / 64];
    int t = threadIdx.x;
    long base = (long)blockIdx.x * CH;
    int m = (int)(((long)nE - base < CH) ? (nE - base) : CH);
    if (t < NBK) cnt[t] = 0;
    __syncthreads();
    // pass 1: bucket count (LDS) + global degree count, int4 loads
    for (int k = t * 4; k < m; k += STPB * 4) {
        if (k + 3 < m) {
            int4 d4 = *(const int4*)(dst + base + k);
            atomicAdd(&cnt[d4.x >> 12], 1); atomicAdd(&deg[d4.x], 1);
            atomicAdd(&cnt[d4.y >> 12], 1); atomicAdd(&deg[d4.y], 1);
            atomicAdd(&cnt[d4.z >> 12], 1); atomicAdd(&deg[d4.z], 1);
            atomicAdd(&cnt[d4.w >> 12], 1); atomicAdd(&deg[d4.w], 1);
        } else {
            int ke = (k + 4 < m) ? (k + 4) : m;
            for (int kk = k; kk < ke; ++kk) {
                int d = dst[base + kk];
                atomicAdd(&cnt[d >> 12], 1); atomicAdd(&deg[d], 1);
            }
        }
    }
    __syncthreads();
    // exclusive scan of 256 counts: wave shfl-scan (4 waves) + cross-wave, 2 barriers
    int v = 0, incl = 0;
    if (t < NBK) {
        v = cnt[t]; incl = v;
#pragma unroll
        for (int o = 1; o < 64; o <<= 1) {
            int u = __shfl_up(incl, o, 64);
            if ((t & 63) >= o) incl += u;
        }
        if ((t & 63) == 63) wsum[t >> 6] = incl;
    }
    __syncthreads();
    if (t < NBK) {
        int wadd = 0;
#pragma unroll
        for (int w = 0; w < 3; ++w) wadd += (w < (t >> 6)) ? wsum[w] : 0;
        int ex = incl - v + wadd;
        sstart[t] = ex;
        cur[t] = ex;
        cbase[t] = v ? atomicAdd(&tails[t], v) : 0;   // reserve global run
    }
    __syncthreads();
    // pass 2: place into LDS, sorted by bucket (int4 re-reads from L2/L3)
    for (int k = t * 4; k < m; k += STPB * 4) {
        if (k + 3 < m) {
            int4 d4 = *(const int4*)(dst + base + k);
            int4 s4 = *(const int4*)(src + base + k);
            { int b = d4.x >> 12; int pos = atomicAdd(&cur[b], 1);
              stage[pos] = ((unsigned)(d4.x & 4095) << 20) | (unsigned)s4.x; bkt[pos] = (unsigned char)b; }
            { int b = d4.y >> 12; int pos = atomicAdd(&cur[b], 1);
              stage[pos] = ((unsigned)(d4.y & 4095) << 20) | (unsigned)s4.y; bkt[pos] = (unsigned char)b; }
            { int b = d4.z >> 12; int pos = atomicAdd(&cur[b], 1);
              stage[pos] = ((unsigned)(d4.z & 4095) << 20) | (unsigned)s4.z; bkt[pos] = (unsigned char)b; }
            { int b = d4.w >> 12; int pos = atomicAdd(&cur[b], 1);
              stage[pos] = ((unsigned)(d4.w & 4095) << 20) | (unsigned)s4.w; bkt[pos] = (unsigned char)b; }
        } else {
            int ke = (k + 4 < m) ? (k + 4) : m;
            for (int kk = k; kk < ke; ++kk) {
                int d = dst[base + kk], s = src[base + kk];
                int b = d >> 12; int pos = atomicAdd(&cur[b], 1);
                stage[pos] = ((unsigned)(d & 4095) << 20) | (unsigned)s; bkt[pos] = (unsigned char)b;
            }
        }
    }
    __syncthreads();
    // burst flush: consecutive threads -> consecutive dests within runs
    for (int k = t; k < m; k += STPB) {
        int b = bkt[k];
        bdata[cbase[b] + (k - sstart[b])] = stage[k];
    }
}

// ---------------- bucket edge-count prefix: P[b] = sum_{b'<b} cnt_b' ----------------
__global__ void bucket_prefix(const int* __restrict__ tails, int* __restrict__ P) {
    __shared__ int lds[NBK];
    int t = threadIdx.x;
    int c = tails[t] - t * CAPB;
    lds[t] = c;
    __syncthreads();
    for (int off = 1; off < NBK; off <<= 1) {
        int u = (t >= off) ? lds[t - off] : 0;
        __syncthreads();
        lds[t] += u;
        __syncthreads();
    }
    P[t] = lds[t] - c;
    if (t == NBK - 1) P[NBK] = lds[t];
}

// ------- per-bucket exact CSR fill, LDS-staged burst flush; degrees from global deg ----
// One block per bucket, 1024 threads (16 waves/CU). Thread t owns nodes [t*4, t*4+4):
// registers hold degrees; shfl-scan builds prefix; fused rowptr + layer-1 writes.
__global__ __launch_bounds__(BTPB) void bucket_csr(const unsigned* __restrict__ bdata,
                                                   const int* __restrict__ tails,
                                                   const int* __restrict__ P,
                                                   const int* __restrict__ deg,
                                                   const float* __restrict__ x,
                                                   const float* __restrict__ W1,
                                                   int* __restrict__ rowptr,
                                                   __half* __restrict__ hs,
                                                   int* __restrict__ col, int n) {
    __shared__ int      off[BNODES];       // 16 KB (prefix -> cursor)
    __shared__ int      wsum[BTPB / 64];   // 16 wave partials
    __shared__ unsigned stg[HSTG];         // 108 KB
    int b = blockIdx.x, t = threadIdx.x;
    int base = b << 12;
    int e0 = b * CAPB, e1 = tails[b];
    int m = e1 - e0;
    int Pb = P[b];
    // own 4 node degrees (registers)
    int node0 = base + t * 4;
    int dloc[4];
    if (node0 + 3 < n) {
        int4 a = *(const int4*)(deg + node0);
        dloc[0] = a.x; dloc[1] = a.y; dloc[2] = a.z; dloc[3] = a.w;
    } else {
#pragma unroll
        for (int k = 0; k < 4; ++k) dloc[k] = (node0 + k < n) ? deg[node0 + k] : 0;
    }
    int loc[4], s = 0;
#pragma unroll
    for (int k = 0; k < 4; ++k) { loc[k] = s; s += dloc[k]; }
    // block scan of per-thread sums: wave shfl-scan + cross-wave
    int incl = s;
#pragma unroll
    for (int o = 1; o < 64; o <<= 1) {
        int u = __shfl_up(incl, o, 64);
        if ((t & 63) >= o) incl += u;
    }
    if ((t & 63) == 63) wsum[t >> 6] = incl;
    __syncthreads();
    int wadd = 0;
#pragma unroll
    for (int w = 0; w < BTPB / 64 - 1; ++w) wadd += (w < (t >> 6)) ? wsum[w] : 0;
    int pex = incl - s + wadd;
#pragma unroll
    for (int k = 0; k < 4; ++k) off[t * 4 + k] = pex + loc[k];
    // fused rowptr + layer-1 (all operands in registers)
    float4 w0 = ((const float4*)W1)[0];
    float4 w1 = ((const float4*)W1)[1];
    if (node0 + 3 < n) {
        int4 rp; rp.x = Pb + pex + loc[0]; rp.y = Pb + pex + loc[1];
        rp.z = Pb + pex + loc[2]; rp.w = Pb + pex + loc[3];
        *(int4*)(rowptr + node0) = rp;
        float4 xv = *(const float4*)(x + node0);
        float xs[4] = {xv.x, xv.y, xv.z, xv.w};
#pragma unroll
        for (int k = 0; k < 4; ++k) {
            float dv = rsqrtf((float)dloc[k] + 1.0f);
            float xd = xs[k] * dv;
            H8 o;
            o.h2[0] = __floats2half2_rn(xd * w0.x, xd * w0.y);
            o.h2[1] = __floats2half2_rn(xd * w0.z, xd * w0.w);
            o.h2[2] = __floats2half2_rn(xd * w1.x, xd * w1.y);
            o.h2[3] = __floats2half2_rn(xd * w1.z, xd * w1.w);
            ((uv4*)hs)[node0 + k] = o.u;
        }
    } else {
#pragma unroll
        for (int k = 0; k < 4; ++k) {
            int node = node0 + k;
            if (node > n) continue;
            rowptr[node] = Pb + pex + loc[k];
            if (node < n) {
                float dv = rsqrtf((float)dloc[k] + 1.0f);
                float xd = x[node] * dv;
                H8 o;
                o.h2[0] = __floats2half2_rn(xd * w0.x, xd * w0.y);
                o.h2[1] = __floats2half2_rn(xd * w0.z, xd * w0.w);
                o.h2[2] = __floats2half2_rn(xd * w1.x, xd * w1.y);
                o.h2[3] = __floats2half2_rn(xd * w1.z, xd * w1.w);
                ((uv4*)hs)[node] = o.u;
            }
        }
    }
    __syncthreads();
    int hmid = off[2048];              // edges in first node-half (pristine prefix)
    // two node-halves; stage in LDS at final offsets, then burst flush
#pragma unroll
    for (int h = 0; h < 2; ++h) {
        int sbeg = h ? hmid : 0;
        int send = h ? m : hmid;
        for (int k = e0 + t; k < e1; k += BTPB) {
            unsigned p = bdata[k];
            int j = p >> 20;
            if ((j >> 11) == h) {
                int pos = atomicAdd(&off[j], 1);
                stg[pos - sbeg] = p & 0xFFFFFu;
            }
        }
        __syncthreads();
        int cntv = send - sbeg;
        for (int k = t; k < cntv; k += BTPB)
            col[Pb + sbeg + k] = (int)stg[k];
        __syncthreads();
    }
}

// ---------------- seed: mark idx nodes (tag 1) + enqueue unique ----------------
__global__ void seed_mark_q(const int* __restrict__ idx, int B, int* __restrict__ mark,
                            int* __restrict__ L, int* __restrict__ qq) {
    int t = threadIdx.x;
    if (t < B) {
        int u = idx[t];
        if (atomicCAS(&mark[u], 0, 1) == 0)
            L[atomicAdd(&qq[7], 1)] = u;
    }
}

__global__ void snap_qb(int* __restrict__ qq, int k) { qq[k] = qq[7]; }

// ------- frontier expansion: tier t processes rows [qq[t-2], qq[t-1]) -------------
__global__ __launch_bounds__(TPB) void expand_f(int* __restrict__ L, int* __restrict__ qq,
                                                int tier,
                                                const int* __restrict__ rowptr,
                                                const int* __restrict__ col,
                                                int* __restrict__ mark) {
    int lo = qq[tier - 2], hi = qq[tier - 1];
    int stride = gridDim.x * blockDim.x;
    for (int r = lo + blockIdx.x * blockDim.x + threadIdx.x; r < hi; r += stride) {
        int u = L[r];
        int e0 = rowptr[u], e1 = rowptr[u + 1];
        for (int k = e0; k < e1; ++k) {
            int s = col[k];
            if (mark[s] == 0 && atomicCAS(&mark[s], 0, tier) == 0)
                L[atomicAdd(&qq[7], 1)] = s;
        }
    }
}

// ---------------- fused pull + node transform over rows [0, qq[bidx]) ------------
// dis recomputed from rowptr diff: rsqrtf(deg+1), bit-identical to stored form.
__global__ void pull_tier(const int* __restrict__ L, const int* __restrict__ qq, int bidx,
                          const int* __restrict__ rowptr, const int* __restrict__ col,
                          const __half* __restrict__ hs_in, const float* __restrict__ bias,
                          const float* __restrict__ W, __half* __restrict__ hs_out) {
    int r = blockIdx.x * blockDim.x + threadIdx.x;
    if (r >= qq[bidx]) return;
    int u = L[r];
    const uv4* hv = (const uv4*)hs_in;
    H8 p; p.u = hv[u];                       // self term
    float2 a0 = __half22float2(p.h2[0]);
    float2 a1 = __half22float2(p.h2[1]);
    float2 a2 = __half22float2(p.h2[2]);
    float2 a3 = __half22float2(p.h2[3]);
    int s = rowptr[u], e = rowptr[u + 1];
    for (int k = s; k < e; ++k) {
        H8 q; q.u = hv[col[k]];
        float2 b0 = __half22float2(q.h2[0]);
        float2 b1 = __half22float2(q.h2[1]);
        float2 b2 = __half22float2(q.h2[2]);
        float2 b3 = __half22float2(q.h2[3]);
        a0.x += b0.x; a0.y += b0.y; a1.x += b1.x; a1.y += b1.y;
        a2.x += b2.x; a2.y += b2.y; a3.x += b3.x; a3.y += b3.y;
    }
    float d = rsqrtf((float)(e - s) + 1.0f);
    float t[8] = {a0.x * d, a0.y * d, a1.x * d, a1.y * d,
                  a2.x * d, a2.y * d, a3.x * d, a3.y * d};
#pragma unroll
    for (int k = 0; k < 8; ++k) {
        float v = t[k] + bias[k];
        t[k] = v > 0.0f ? v : 0.0f;
    }
    float h[8];
#pragma unroll
    for (int j = 0; j < 8; ++j) {
        float acc = 0.0f;
#pragma unroll
        for (int k = 0; k < 8; ++k) acc += t[k] * W[k * 8 + j];
        h[j] = acc * d;
    }
    H8 o;
    o.h2[0] = __floats2half2_rn(h[0], h[1]);
    o.h2[1] = __floats2half2_rn(h[2], h[3]);
    o.h2[2] = __floats2half2_rn(h[4], h[5]);
    o.h2[3] = __floats2half2_rn(h[6], h[7]);
    ((uv4*)hs_out)[u] = o.u;
}

// ---------------- final: out[t][:] = dis*(sum+self) + b4, for the idx nodes ------
__global__ void pull_final(const int* __restrict__ idx, int B,
                           const int* __restrict__ rowptr, const int* __restrict__ col,
                           const __half* __restrict__ hs_in,
                           const float* __restrict__ b4, float* __restrict__ out) {
    int t = blockIdx.x * blockDim.x + threadIdx.x;
    if (t >= B) return;
    int u = idx[t];
    const uv4* hv = (const uv4*)hs_in;
    H8 p; p.u = hv[u];
    float2 a0 = __half22float2(p.h2[0]);
    float2 a1 = __half22float2(p.h2[1]);
    float2 a2 = __half22float2(p.h2[2]);
    float2 a3 = __half22float2(p.h2[3]);
    int s = rowptr[u], e = rowptr[u + 1];
    for (int k = s; k < e; ++k) {
        H8 q; q.u = hv[col[k]];
        float2 b0 = __half22float2(q.h2[0]);
        float2 b1 = __half22float2(q.h2[1]);
        float2 b2 = __half22float2(q.h2[2]);
        float2 b3 = __half22float2(q.h2[3]);
        a0.x += b0.x; a0.y += b0.y; a1.x += b1.x; a1.y += b1.y;
        a2.x += b2.x; a2.y += b2.y; a3.x += b3.x; a3.y += b3.y;
    }
    float d = rsqrtf((float)(e - s) + 1.0f);
    float* op = out + (size_t)t * 8;
    op[0] = a0.x * d + b4[0]; op[1] = a0.y * d + b4[1];
    op[2] = a1.x * d + b4[2]; op[3] = a1.y * d + b4[3];
    op[4] = a2.x * d + b4[4]; op[5] = a2.y * d + b4[5];
    op[6] = a3.x * d + b4[6]; op[7] = a3.y * d + b4[7];
}

extern "C" void kernel_launch(void* const* d_in, const int* in_sizes, int n_in,
                              void* d_out, int out_size, void* d_ws, size_t ws_size,
                              hipStream_t stream) {
    const float* x   = (const float*)d_in[0];
    const int*   ei  = (const int*)d_in[1];
    const int*   idx = (const int*)d_in[2];
    const float* W1  = (const float*)d_in[3];
    const float* b1  = (const float*)d_in[4];
    const float* W2  = (const float*)d_in[5];
    const float* b2  = (const float*)d_in[6];
    const float* W3  = (const float*)d_in[7];
    const float* b3  = (const float*)d_in[8];
    const float* W4  = (const float*)d_in[9];
    const float* b4  = (const float*)d_in[10];

    const int n = in_sizes[0];      // 1,000,000 nodes (n <= 2^20 for packing)
    const int E = in_sizes[1] / 2;  // 10,000,000 edges
    const int B = in_sizes[2];      // 64 graphs

    const int* src = ei;
    const int* dst = ei + E;

    const int NB = (n + BNODES - 1) / BNODES;            // 245 buckets

    // workspace (int elements):
    size_t o_mark = 0;
    size_t o_deg  = o_mark + (size_t)n;                  // adjacent to mark: single memset
    size_t o_rp   = o_deg  + (size_t)n;                  // n+1 (+pad)
    size_t o_hsA  = o_rp   + (size_t)n + 8;
    size_t o_L    = o_hsA  + (size_t)n * 4;
    size_t o_col  = o_L    + CAP_L;
    size_t o_bd   = o_col  + (size_t)E;                  // bdata; hsB aliases its base
    size_t o_sm   = o_bd   + (size_t)NB * CAPB;

    int*      mark   = (int*)d_ws + o_mark;
    int*      deg    = (int*)d_ws + o_deg;
    int*      rowptr = (int*)d_ws + o_rp;
    __half*   hsA    = (__half*)((int*)d_ws + o_hsA);
    int*      L      = (int*)d_ws + o_L;
    int*      col    = (int*)d_ws + o_col;
    unsigned* bdata  = (unsigned*)((int*)d_ws + o_bd);
    __half*   hsB    = (__half*)bdata;                   // bdata dead after bucket_csr
    int*      tails  = (int*)d_ws + o_sm;
    int*      P      = tails + NBK + 8;                  // NBK+1 entries
    int*      qq     = P + NBK + 8;                      // [0..4]=tier bounds, [7]=qtail

    const int gs  = (int)(((long)E + CH - 1) / CH);      // 1628
    const int nb2 = CAP_L / TPB;                         // 1024

    // ---- init (mark+deg contiguous -> one memset) ----
    (void)hipMemsetAsync(mark, 0, (size_t)n * 2 * sizeof(int), stream);
    (void)hipMemsetAsync(qq, 0, 16 * sizeof(int), stream);
    init_tails<<<1, NBK, 0, stream>>>(tails);

    // ---- bucket partition (LDS counting sort, burst flush) + global degree count ----
    scatter_sort<<<gs, STPB, 0, stream>>>(dst, src, tails, deg, bdata, E);

    // ---- exact full CSR from buckets (LDS-staged; fuses rowptr + layer-1) ----
    bucket_prefix<<<1, NBK, 0, stream>>>(tails, P);
    bucket_csr<<<NB, BTPB, 0, stream>>>(bdata, tails, P, deg, x, W1, rowptr, hsA, col, n);

    // ---- frontier cone expansion (tiny) ----
    seed_mark_q<<<1, 64, 0, stream>>>(idx, B, mark, L, qq);
    snap_qb<<<1, 1, 0, stream>>>(qq, 1);
    expand_f<<<64, TPB, 0, stream>>>(L, qq, 2, rowptr, col, mark);
    snap_qb<<<1, 1, 0, stream>>>(qq, 2);
    expand_f<<<128, TPB, 0, stream>>>(L, qq, 3, rowptr, col, mark);
    snap_qb<<<1, 1, 0, stream>>>(qq, 3);
    expand_f<<<256, TPB, 0, stream>>>(L, qq, 4, rowptr, col, mark);
    snap_qb<<<1, 1, 0, stream>>>(qq, 4);

    // ---- layers ----
    pull_tier<<<nb2, TPB, 0, stream>>>(L, qq, 4, rowptr, col, hsA, b1, W2, hsB);
    pull_tier<<<nb2, TPB, 0, stream>>>(L, qq, 3, rowptr, col, hsB, b2, W3, hsA);
    pull_tier<<<nb2, TPB, 0, stream>>>(L, qq, 2, rowptr, col, hsA, b3, W4, hsB);
    pull_final<<<1, 64, 0, stream>>>(idx, B, rowptr, col, hsB, b4, (float*)d_out);
}

// Round 5
// 450.192 us; speedup vs baseline: 1.6688x; 1.6688x over previous
//
#include <hip/hip_runtime.h>
#include <hip/hip_fp16.h>

#define TPB 256
#define STPB 512           // threads for scatter_sort
#define BTPB 512           // threads for bucket_csr
#define NBK 256            // bucket index space (dst >> 12); 245 used
#define BNODES 4096        // nodes per bucket
#define CH 6144            // edges per scatter_sort chunk (~34 KB LDS -> 4 blocks/CU)
#define CAPB 45056         // fixed bucket capacity (mean 40960 + 20 sigma)
#define CAP_L 262144       // cone row cap (|marked| ~ 92K mean)
#define HSTG 27648         // per-half LDS stage capacity (108 KB; mean 20480 + 50 sigma)

typedef unsigned int uv4 __attribute__((ext_vector_type(4)));
union H8 { uv4 u; __half2 h2[4]; };

// ---------------- init: tails[b] = b * CAPB ----------------
__global__ void init_tails(int* __restrict__ tails) {
    tails[threadIdx.x] = threadIdx.x * CAPB;
}

// ------- partition edges into fixed-capacity buckets; LDS counting sort, burst flush ---
// payload: (dstLow12 << 20) | src  (exactly 32 bits; requires n <= 2^20)
// NO global atomics here (round-4 lesson: they cost ~31 B HBM traffic each).
__global__ __launch_bounds__(STPB) void scatter_sort(const int* __restrict__ dst,
                                                     const int* __restrict__ src,
                                                     int* __restrict__ tails,
                                                     unsigned* __restrict__ bdata, int nE) {
    __shared__ unsigned      stage[CH];      // 24 KB
    __shared__ unsigned char bkt[CH];        // 6 KB
    __shared__ int cnt[NBK], sstart[NBK], cur[NBK], cbase[NBK];   // 4 KB
    __shared__ int wsum[STPB / 64];
    int t = threadIdx.x;
    long base = (long)blockIdx.x * CH;
    int m = (int)(((long)nE - base < CH) ? (nE - base) : CH);
    if (t < NBK) cnt[t] = 0;
    __syncthreads();
    // pass 1: bucket count (LDS atomics only), int4 loads
    for (int k = t * 4; k < m; k += STPB * 4) {
        if (k + 3 < m) {
            int4 d4 = *(const int4*)(dst + base + k);
            atomicAdd(&cnt[d4.x >> 12], 1);
            atomicAdd(&cnt[d4.y >> 12], 1);
            atomicAdd(&cnt[d4.z >> 12], 1);
            atomicAdd(&cnt[d4.w >> 12], 1);
        } else {
            int ke = (k + 4 < m) ? (k + 4) : m;
            for (int kk = k; kk < ke; ++kk)
                atomicAdd(&cnt[dst[base + kk] >> 12], 1);
        }
    }
    __syncthreads();
    // exclusive scan of 256 counts: wave shfl-scan (4 waves) + cross-wave, 2 barriers
    int v = 0, incl = 0;
    if (t < NBK) {
        v = cnt[t]; incl = v;
#pragma unroll
        for (int o = 1; o < 64; o <<= 1) {
            int u = __shfl_up(incl, o, 64);
            if ((t & 63) >= o) incl += u;
        }
        if ((t & 63) == 63) wsum[t >> 6] = incl;
    }
    __syncthreads();
    if (t < NBK) {
        int wadd = 0;
#pragma unroll
        for (int w = 0; w < 3; ++w) wadd += (w < (t >> 6)) ? wsum[w] : 0;
        int ex = incl - v + wadd;
        sstart[t] = ex;
        cur[t] = ex;
        cbase[t] = v ? atomicAdd(&tails[t], v) : 0;   // reserve global run
    }
    __syncthreads();
    // pass 2: place into LDS, sorted by bucket (int4 re-reads from L2/L3)
    for (int k = t * 4; k < m; k += STPB * 4) {
        if (k + 3 < m) {
            int4 d4 = *(const int4*)(dst + base + k);
            int4 s4 = *(const int4*)(src + base + k);
            { int b = d4.x >> 12; int pos = atomicAdd(&cur[b], 1);
              stage[pos] = ((unsigned)(d4.x & 4095) << 20) | (unsigned)s4.x; bkt[pos] = (unsigned char)b; }
            { int b = d4.y >> 12; int pos = atomicAdd(&cur[b], 1);
              stage[pos] = ((unsigned)(d4.y & 4095) << 20) | (unsigned)s4.y; bkt[pos] = (unsigned char)b; }
            { int b = d4.z >> 12; int pos = atomicAdd(&cur[b], 1);
              stage[pos] = ((unsigned)(d4.z & 4095) << 20) | (unsigned)s4.z; bkt[pos] = (unsigned char)b; }
            { int b = d4.w >> 12; int pos = atomicAdd(&cur[b], 1);
              stage[pos] = ((unsigned)(d4.w & 4095) << 20) | (unsigned)s4.w; bkt[pos] = (unsigned char)b; }
        } else {
            int ke = (k + 4 < m) ? (k + 4) : m;
            for (int kk = k; kk < ke; ++kk) {
                int d = dst[base + kk], s = src[base + kk];
                int b = d >> 12; int pos = atomicAdd(&cur[b], 1);
                stage[pos] = ((unsigned)(d & 4095) << 20) | (unsigned)s; bkt[pos] = (unsigned char)b;
            }
        }
    }
    __syncthreads();
    // burst flush: consecutive threads -> consecutive dests within runs
    for (int k = t; k < m; k += STPB) {
        int b = bkt[k];
        bdata[cbase[b] + (k - sstart[b])] = stage[k];
    }
}

// ---------------- bucket edge-count prefix: P[b] = sum_{b'<b} cnt_b' ----------------
__global__ void bucket_prefix(const int* __restrict__ tails, int* __restrict__ P) {
    __shared__ int lds[NBK];
    int t = threadIdx.x;
    int c = tails[t] - t * CAPB;
    lds[t] = c;
    __syncthreads();
    for (int off = 1; off < NBK; off <<= 1) {
        int u = (t >= off) ? lds[t - off] : 0;
        __syncthreads();
        lds[t] += u;
        __syncthreads();
    }
    P[t] = lds[t] - c;
    if (t == NBK - 1) P[NBK] = lds[t];
}

// ------- per-bucket exact CSR build, LDS-staged burst flush (no write amplification) ---
// One block per bucket. off[]: counts -> prefix -> cursor, in place (LDS atomics only).
// Two node-halves: filter-place edges into LDS stage at final offsets, flush contiguous.
// Also fuses layer-1: hs[node] = pack(x[node]*dis*W1row). No dis array (recomputed later).
__global__ __launch_bounds__(BTPB) void bucket_csr(const unsigned* __restrict__ bdata,
                                                   const int* __restrict__ tails,
                                                   const int* __restrict__ P,
                                                   const float* __restrict__ x,
                                                   const float* __restrict__ W1,
                                                   int* __restrict__ rowptr,
                                                   __half* __restrict__ hs,
                                                   int* __restrict__ col, int n) {
    __shared__ int      off[BNODES];   // 16 KB
    __shared__ int      part[BTPB];    // 2 KB (scan partials)
    __shared__ unsigned stg[HSTG];     // 108 KB
    int b = blockIdx.x, t = threadIdx.x;
    int base = b << 12;
    for (int j = t; j < BNODES; j += BTPB) off[j] = 0;
    __syncthreads();
    int e0 = b * CAPB, e1 = tails[b];
    int m = e1 - e0;
    // pass 1: degree count into off (plain loads: warm L2 for re-reads)
    for (int k = e0 + t; k < e1; k += BTPB)
        atomicAdd(&off[bdata[k] >> 20], 1);
    __syncthreads();
    // in-place scan of 4096 counts: thread t owns [t*8, t*8+8)
    int loc[8];
    int s = 0;
#pragma unroll
    for (int k = 0; k < 8; ++k) { loc[k] = s; s += off[t * 8 + k]; }
    part[t] = s;
    __syncthreads();
    for (int o = 1; o < BTPB; o <<= 1) {
        int u = (t >= o) ? part[t - o] : 0;
        __syncthreads();
        part[t] += u;
        __syncthreads();
    }
    int pex = part[t] - s;
#pragma unroll
    for (int k = 0; k < 8; ++k) off[t * 8 + k] = pex + loc[k];   // own slots only
    __syncthreads();
    int Pb = P[b];
    int hmid = off[2048];              // edges in first node-half (pristine prefix)
    // rowptr + fused layer-1 (deg recovered from prefix differences)
    float4 w0 = ((const float4*)W1)[0];
    float4 w1 = ((const float4*)W1)[1];
    for (int j = t; j < BNODES; j += BTPB) {
        int node = base + j;
        if (node > n) continue;
        rowptr[node] = Pb + off[j];
        if (node < n) {
            int degj = ((j < BNODES - 1) ? off[j + 1] : m) - off[j];
            float dv = rsqrtf((float)degj + 1.0f);
            float xd = x[node] * dv;
            H8 o;
            o.h2[0] = __floats2half2_rn(xd * w0.x, xd * w0.y);
            o.h2[1] = __floats2half2_rn(xd * w0.z, xd * w0.w);
            o.h2[2] = __floats2half2_rn(xd * w1.x, xd * w1.y);
            o.h2[3] = __floats2half2_rn(xd * w1.z, xd * w1.w);
            ((uv4*)hs)[node] = o.u;
        }
    }
    __syncthreads();
    // pass 2: two node-halves; stage in LDS at final offsets, then burst flush
#pragma unroll
    for (int h = 0; h < 2; ++h) {
        int sbeg = h ? hmid : 0;
        int send = h ? m : hmid;
        for (int k = e0 + t; k < e1; k += BTPB) {
            unsigned p = bdata[k];
            int j = p >> 20;
            if ((j >> 11) == h) {
                int pos = atomicAdd(&off[j], 1);
                stg[pos - sbeg] = p & 0xFFFFFu;
            }
        }
        __syncthreads();
        int cntv = send - sbeg;
        for (int k = t; k < cntv; k += BTPB)
            col[Pb + sbeg + k] = (int)stg[k];
        __syncthreads();
    }
}

// ---------------- seed: mark idx nodes (tag 1) + enqueue unique ----------------
__global__ void seed_mark_q(const int* __restrict__ idx, int B, int* __restrict__ mark,
                            int* __restrict__ L, int* __restrict__ qq) {
    int t = threadIdx.x;
    if (t < B) {
        int u = idx[t];
        if (atomicCAS(&mark[u], 0, 1) == 0)
            L[atomicAdd(&qq[7], 1)] = u;
    }
}

__global__ void snap_qb(int* __restrict__ qq, int k) { qq[k] = qq[7]; }

// ------- frontier expansion: tier t processes rows [qq[t-2], qq[t-1]) -------------
__global__ __launch_bounds__(TPB) void expand_f(int* __restrict__ L, int* __restrict__ qq,
                                                int tier,
                                                const int* __restrict__ rowptr,
                                                const int* __restrict__ col,
                                                int* __restrict__ mark) {
    int lo = qq[tier - 2], hi = qq[tier - 1];
    int stride = gridDim.x * blockDim.x;
    for (int r = lo + blockIdx.x * blockDim.x + threadIdx.x; r < hi; r += stride) {
        int u = L[r];
        int e0 = rowptr[u], e1 = rowptr[u + 1];
        for (int k = e0; k < e1; ++k) {
            int s = col[k];
            if (mark[s] == 0 && atomicCAS(&mark[s], 0, tier) == 0)
                L[atomicAdd(&qq[7], 1)] = s;
        }
    }
}

// ---------------- fused pull + node transform over rows [0, qq[bidx]) ------------
// dis recomputed from rowptr diff: rsqrtf(deg+1), bit-identical to stored form.
__global__ void pull_tier(const int* __restrict__ L, const int* __restrict__ qq, int bidx,
                          const int* __restrict__ rowptr, const int* __restrict__ col,
                          const __half* __restrict__ hs_in, const float* __restrict__ bias,
                          const float* __restrict__ W, __half* __restrict__ hs_out) {
    int r = blockIdx.x * blockDim.x + threadIdx.x;
    if (r >= qq[bidx]) return;
    int u = L[r];
    const uv4* hv = (const uv4*)hs_in;
    H8 p; p.u = hv[u];                       // self term
    float2 a0 = __half22float2(p.h2[0]);
    float2 a1 = __half22float2(p.h2[1]);
    float2 a2 = __half22float2(p.h2[2]);
    float2 a3 = __half22float2(p.h2[3]);
    int s = rowptr[u], e = rowptr[u + 1];
    for (int k = s; k < e; ++k) {
        H8 q; q.u = hv[col[k]];
        float2 b0 = __half22float2(q.h2[0]);
        float2 b1 = __half22float2(q.h2[1]);
        float2 b2 = __half22float2(q.h2[2]);
        float2 b3 = __half22float2(q.h2[3]);
        a0.x += b0.x; a0.y += b0.y; a1.x += b1.x; a1.y += b1.y;
        a2.x += b2.x; a2.y += b2.y; a3.x += b3.x; a3.y += b3.y;
    }
    float d = rsqrtf((float)(e - s) + 1.0f);
    float t[8] = {a0.x * d, a0.y * d, a1.x * d, a1.y * d,
                  a2.x * d, a2.y * d, a3.x * d, a3.y * d};
#pragma unroll
    for (int k = 0; k < 8; ++k) {
        float v = t[k] + bias[k];
        t[k] = v > 0.0f ? v : 0.0f;
    }
    float h[8];
#pragma unroll
    for (int j = 0; j < 8; ++j) {
        float acc = 0.0f;
#pragma unroll
        for (int k = 0; k < 8; ++k) acc += t[k] * W[k * 8 + j];
        h[j] = acc * d;
    }
    H8 o;
    o.h2[0] = __floats2half2_rn(h[0], h[1]);
    o.h2[1] = __floats2half2_rn(h[2], h[3]);
    o.h2[2] = __floats2half2_rn(h[4], h[5]);
    o.h2[3] = __floats2half2_rn(h[6], h[7]);
    ((uv4*)hs_out)[u] = o.u;
}

// ---------------- final: out[t][:] = dis*(sum+self) + b4, for the idx nodes ------
__global__ void pull_final(const int* __restrict__ idx, int B,
                           const int* __restrict__ rowptr, const int* __restrict__ col,
                           const __half* __restrict__ hs_in,
                           const float* __restrict__ b4, float* __restrict__ out) {
    int t = blockIdx.x * blockDim.x + threadIdx.x;
    if (t >= B) return;
    int u = idx[t];
    const uv4* hv = (const uv4*)hs_in;
    H8 p; p.u = hv[u];
    float2 a0 = __half22float2(p.h2[0]);
    float2 a1 = __half22float2(p.h2[1]);
    float2 a2 = __half22float2(p.h2[2]);
    float2 a3 = __half22float2(p.h2[3]);
    int s = rowptr[u], e = rowptr[u + 1];
    for (int k = s; k < e; ++k) {
        H8 q; q.u = hv[col[k]];
        float2 b0 = __half22float2(q.h2[0]);
        float2 b1 = __half22float2(q.h2[1]);
        float2 b2 = __half22float2(q.h2[2]);
        float2 b3 = __half22float2(q.h2[3]);
        a0.x += b0.x; a0.y += b0.y; a1.x += b1.x; a1.y += b1.y;
        a2.x += b2.x; a2.y += b2.y; a3.x += b3.x; a3.y += b3.y;
    }
    float d = rsqrtf((float)(e - s) + 1.0f);
    float* op = out + (size_t)t * 8;
    op[0] = a0.x * d + b4[0]; op[1] = a0.y * d + b4[1];
    op[2] = a1.x * d + b4[2]; op[3] = a1.y * d + b4[3];
    op[4] = a2.x * d + b4[4]; op[5] = a2.y * d + b4[5];
    op[6] = a3.x * d + b4[6]; op[7] = a3.y * d + b4[7];
}

extern "C" void kernel_launch(void* const* d_in, const int* in_sizes, int n_in,
                              void* d_out, int out_size, void* d_ws, size_t ws_size,
                              hipStream_t stream) {
    const float* x   = (const float*)d_in[0];
    const int*   ei  = (const int*)d_in[1];
    const int*   idx = (const int*)d_in[2];
    const float* W1  = (const float*)d_in[3];
    const float* b1  = (const float*)d_in[4];
    const float* W2  = (const float*)d_in[5];
    const float* b2  = (const float*)d_in[6];
    const float* W3  = (const float*)d_in[7];
    const float* b3  = (const float*)d_in[8];
    const float* W4  = (const float*)d_in[9];
    const float* b4  = (const float*)d_in[10];

    const int n = in_sizes[0];      // 1,000,000 nodes (n <= 2^20 for packing)
    const int E = in_sizes[1] / 2;  // 10,000,000 edges
    const int B = in_sizes[2];      // 64 graphs

    const int* src = ei;
    const int* dst = ei + E;

    const int NB = (n + BNODES - 1) / BNODES;            // 245 buckets

    // workspace (int elements):
    size_t o_mark = 0;
    size_t o_rp   = o_mark + (size_t)n;                  // n+1 (+pad)
    size_t o_hsA  = o_rp   + (size_t)n + 8;
    size_t o_L    = o_hsA  + (size_t)n * 4;
    size_t o_col  = o_L    + CAP_L;
    size_t o_bd   = o_col  + (size_t)E;                  // bdata; hsB aliases its base
    size_t o_sm   = o_bd   + (size_t)NB * CAPB;

    int*      mark   = (int*)d_ws + o_mark;
    int*      rowptr = (int*)d_ws + o_rp;
    __half*   hsA    = (__half*)((int*)d_ws + o_hsA);
    int*      L      = (int*)d_ws + o_L;
    int*      col    = (int*)d_ws + o_col;
    unsigned* bdata  = (unsigned*)((int*)d_ws + o_bd);
    __half*   hsB    = (__half*)bdata;                   // bdata dead after bucket_csr
    int*      tails  = (int*)d_ws + o_sm;
    int*      P      = tails + NBK + 8;                  // NBK+1 entries
    int*      qq     = P + NBK + 8;                      // [0..4]=tier bounds, [7]=qtail

    const int gs  = (int)(((long)E + CH - 1) / CH);      // 1628
    const int nb2 = CAP_L / TPB;                         // 1024

    // ---- init ----
    (void)hipMemsetAsync(mark, 0, (size_t)n * sizeof(int), stream);
    (void)hipMemsetAsync(qq, 0, 16 * sizeof(int), stream);
    init_tails<<<1, NBK, 0, stream>>>(tails);

    // ---- bucket partition (LDS counting sort, burst flush) ----
    scatter_sort<<<gs, STPB, 0, stream>>>(dst, src, tails, bdata, E);

    // ---- exact full CSR from buckets (LDS-staged; fuses rowptr + layer-1) ----
    bucket_prefix<<<1, NBK, 0, stream>>>(tails, P);
    bucket_csr<<<NB, BTPB, 0, stream>>>(bdata, tails, P, x, W1, rowptr, hsA, col, n);

    // ---- frontier cone expansion (tiny) ----
    seed_mark_q<<<1, 64, 0, stream>>>(idx, B, mark, L, qq);
    snap_qb<<<1, 1, 0, stream>>>(qq, 1);
    expand_f<<<64, TPB, 0, stream>>>(L, qq, 2, rowptr, col, mark);
    snap_qb<<<1, 1, 0, stream>>>(qq, 2);
    expand_f<<<128, TPB, 0, stream>>>(L, qq, 3, rowptr, col, mark);
    snap_qb<<<1, 1, 0, stream>>>(qq, 3);
    expand_f<<<256, TPB, 0, stream>>>(L, qq, 4, rowptr, col, mark);
    snap_qb<<<1, 1, 0, stream>>>(qq, 4);

    // ---- layers ----
    pull_tier<<<nb2, TPB, 0, stream>>>(L, qq, 4, rowptr, col, hsA, b1, W2, hsB);
    pull_tier<<<nb2, TPB, 0, stream>>>(L, qq, 3, rowptr, col, hsB, b2, W3, hsA);
    pull_tier<<<nb2, TPB, 0, stream>>>(L, qq, 2, rowptr, col, hsA, b3, W4, hsB);
    pull_final<<<1, 64, 0, stream>>>(idx, B, rowptr, col, hsB, b4, (float*)d_out);
}

// Round 6
// 421.277 us; speedup vs baseline: 1.7833x; 1.0686x over previous
//
#include <hip/hip_runtime.h>
#include <hip/hip_fp16.h>

#define TPB 256
#define STPB 512           // threads for scatter_sort
#define BTPB 512           // threads for quarter_csr
#define NBK 256            // bucket index space (dst >> 12); 245 used
#define BNODES 4096        // nodes per bucket
#define QNODES 1024        // nodes per quarter
#define CH 6144            // edges per scatter_sort chunk (~34 KB LDS -> 4 blocks/CU)
#define CAPB 45056         // fixed bucket capacity (mean 40960 + 20 sigma)
#define QSTG 12288         // quarter LDS stage capacity (48 KB; mean 10240 + 20 sigma)
#define CAP_L 262144       // cone row cap (|marked| ~ 92K mean)

typedef unsigned int uv4 __attribute__((ext_vector_type(4)));
union H8 { uv4 u; __half2 h2[4]; };

// ---------------- init: tails[b] = b * CAPB ----------------
__global__ void init_tails(int* __restrict__ tails) {
    tails[threadIdx.x] = threadIdx.x * CAPB;
}

// ------- partition edges into fixed-capacity buckets; LDS counting sort, burst flush ---
// payload: (dstLow12 << 20) | src  (exactly 32 bits; requires n <= 2^20)
// NO global atomics here (round-4 lesson: they cost ~31 B HBM traffic each).
__global__ __launch_bounds__(STPB) void scatter_sort(const int* __restrict__ dst,
                                                     const int* __restrict__ src,
                                                     int* __restrict__ tails,
                                                     unsigned* __restrict__ bdata, int nE) {
    __shared__ unsigned      stage[CH];      // 24 KB
    __shared__ unsigned char bkt[CH];        // 6 KB
    __shared__ int cnt[NBK], sstart[NBK], cur[NBK], cbase[NBK];   // 4 KB
    __shared__ int wsum[STPB / 64];
    int t = threadIdx.x;
    long base = (long)blockIdx.x * CH;
    int m = (int)(((long)nE - base < CH) ? (nE - base) : CH);
    if (t < NBK) cnt[t] = 0;
    __syncthreads();
    // pass 1: bucket count (LDS atomics only), int4 loads
    for (int k = t * 4; k < m; k += STPB * 4) {
        if (k + 3 < m) {
            int4 d4 = *(const int4*)(dst + base + k);
            atomicAdd(&cnt[d4.x >> 12], 1);
            atomicAdd(&cnt[d4.y >> 12], 1);
            atomicAdd(&cnt[d4.z >> 12], 1);
            atomicAdd(&cnt[d4.w >> 12], 1);
        } else {
            int ke = (k + 4 < m) ? (k + 4) : m;
            for (int kk = k; kk < ke; ++kk)
                atomicAdd(&cnt[dst[base + kk] >> 12], 1);
        }
    }
    __syncthreads();
    // exclusive scan of 256 counts: wave shfl-scan (4 waves) + cross-wave, 2 barriers
    int v = 0, incl = 0;
    if (t < NBK) {
        v = cnt[t]; incl = v;
#pragma unroll
        for (int o = 1; o < 64; o <<= 1) {
            int u = __shfl_up(incl, o, 64);
            if ((t & 63) >= o) incl += u;
        }
        if ((t & 63) == 63) wsum[t >> 6] = incl;
    }
    __syncthreads();
    if (t < NBK) {
        int wadd = 0;
#pragma unroll
        for (int w = 0; w < 3; ++w) wadd += (w < (t >> 6)) ? wsum[w] : 0;
        int ex = incl - v + wadd;
        sstart[t] = ex;
        cur[t] = ex;
        cbase[t] = v ? atomicAdd(&tails[t], v) : 0;   // reserve global run
    }
    __syncthreads();
    // pass 2: place into LDS, sorted by bucket (int4 re-reads from L2/L3)
    for (int k = t * 4; k < m; k += STPB * 4) {
        if (k + 3 < m) {
            int4 d4 = *(const int4*)(dst + base + k);
            int4 s4 = *(const int4*)(src + base + k);
            { int b = d4.x >> 12; int pos = atomicAdd(&cur[b], 1);
              stage[pos] = ((unsigned)(d4.x & 4095) << 20) | (unsigned)s4.x; bkt[pos] = (unsigned char)b; }
            { int b = d4.y >> 12; int pos = atomicAdd(&cur[b], 1);
              stage[pos] = ((unsigned)(d4.y & 4095) << 20) | (unsigned)s4.y; bkt[pos] = (unsigned char)b; }
            { int b = d4.z >> 12; int pos = atomicAdd(&cur[b], 1);
              stage[pos] = ((unsigned)(d4.z & 4095) << 20) | (unsigned)s4.z; bkt[pos] = (unsigned char)b; }
            { int b = d4.w >> 12; int pos = atomicAdd(&cur[b], 1);
              stage[pos] = ((unsigned)(d4.w & 4095) << 20) | (unsigned)s4.w; bkt[pos] = (unsigned char)b; }
        } else {
            int ke = (k + 4 < m) ? (k + 4) : m;
            for (int kk = k; kk < ke; ++kk) {
                int d = dst[base + kk], s = src[base + kk];
                int b = d >> 12; int pos = atomicAdd(&cur[b], 1);
                stage[pos] = ((unsigned)(d & 4095) << 20) | (unsigned)s; bkt[pos] = (unsigned char)b;
            }
        }
    }
    __syncthreads();
    // burst flush: consecutive threads -> consecutive dests within runs
    for (int k = t; k < m; k += STPB) {
        int b = bkt[k];
        bdata[cbase[b] + (k - sstart[b])] = stage[k];
    }
}

// ---------------- bucket edge-count prefix: P[b] = sum_{b'<b} cnt_b' ----------------
__global__ void bucket_prefix(const int* __restrict__ tails, int* __restrict__ P) {
    __shared__ int lds[NBK];
    int t = threadIdx.x;
    int c = tails[t] - t * CAPB;
    lds[t] = c;
    __syncthreads();
    for (int off = 1; off < NBK; off <<= 1) {
        int u = (t >= off) ? lds[t - off] : 0;
        __syncthreads();
        lds[t] += u;
        __syncthreads();
    }
    P[t] = lds[t] - c;
    if (t == NBK - 1) P[NBK] = lds[t];
}

// ------- per-QUARTER exact CSR build (4 blocks per bucket = 980 blocks, 2 blocks/CU) ---
// Each block owns 1024 nodes; scans the parent bucket's edges twice (count, fill),
// filtering on quarter id. Qb (edges in earlier quarters) counted for free in pass 1.
// LDS-staged burst flush (round-2/3 lesson: never scatter 4B writes to global).
// Fuses layer-1: hs[node] = pack(x[node]*dis*W1row).
__global__ __launch_bounds__(BTPB) void quarter_csr(const unsigned* __restrict__ bdata,
                                                    const int* __restrict__ tails,
                                                    const int* __restrict__ P,
                                                    const float* __restrict__ x,
                                                    const float* __restrict__ W1,
                                                    int* __restrict__ rowptr,
                                                    __half* __restrict__ hs,
                                                    int* __restrict__ col, int n) {
    __shared__ int      off[QNODES];       // 4 KB (counts -> prefix -> cursor)
    __shared__ int      wsum[BTPB / 64];   // scan wave partials
    __shared__ int      wred[BTPB / 64];   // Qb reduction partials
    __shared__ int      sQb, sTot;
    __shared__ unsigned stg[QSTG];         // 48 KB
    int bid = blockIdx.x, t = threadIdx.x;
    int b = bid >> 2, q = bid & 3;
    int e0 = b * CAPB, e1 = tails[b];
    for (int j = t; j < QNODES; j += BTPB) off[j] = 0;
    __syncthreads();
    // pass 1: count own quarter's degrees + tally edges of earlier quarters (Qb)
    int before = 0;
    for (int k = e0 + t * 4; k < e1; k += BTPB * 4) {
        if (k + 3 < e1) {
            uv4 p4 = *(const uv4*)(bdata + k);
#pragma unroll
            for (int z = 0; z < 4; ++z) {
                int j = (int)(p4[z] >> 20); int jq = j >> 10;
                if (jq == q) atomicAdd(&off[j & 1023], 1);
                before += (jq < q) ? 1 : 0;
            }
        } else {
            for (int kk = k; kk < e1; ++kk) {
                int j = (int)(bdata[kk] >> 20); int jq = j >> 10;
                if (jq == q) atomicAdd(&off[j & 1023], 1);
                before += (jq < q) ? 1 : 0;
            }
        }
    }
#pragma unroll
    for (int o = 32; o > 0; o >>= 1) before += __shfl_down(before, o, 64);
    if ((t & 63) == 0) wred[t >> 6] = before;
    __syncthreads();                        // counts + wred complete
    if (t == 0) {
        int s = 0;
#pragma unroll
        for (int w = 0; w < BTPB / 64; ++w) s += wred[w];
        sQb = s;
    }
    // scan 1024 counts: thread t owns off[2t], off[2t+1]
    int a = off[2 * t], c = off[2 * t + 1];
    int s2 = a + c;
    int incl = s2;
#pragma unroll
    for (int o = 1; o < 64; o <<= 1) {
        int u = __shfl_up(incl, o, 64);
        if ((t & 63) >= o) incl += u;
    }
    if ((t & 63) == 63) wsum[t >> 6] = incl;
    __syncthreads();                        // wsum + sQb visible
    int wadd = 0;
#pragma unroll
    for (int w = 0; w < BTPB / 64 - 1; ++w) wadd += (w < (t >> 6)) ? wsum[w] : 0;
    int pex = incl - s2 + wadd;
    off[2 * t]     = pex;
    off[2 * t + 1] = pex + a;
    if (t == BTPB - 1) sTot = pex + s2;     // quarter's total edge count
    int PbQb = P[b] + sQb;
    // fused rowptr + layer-1 for own 2 nodes (deg = a, c; all in registers)
    {
        int node0 = (b << 12) + (q << 10) + 2 * t;
        float4 w0 = ((const float4*)W1)[0];
        float4 w1 = ((const float4*)W1)[1];
        if (node0 + 1 < n) {
            int2 rp; rp.x = PbQb + pex; rp.y = PbQb + pex + a;
            *(int2*)(rowptr + node0) = rp;
            float2 xv = *(const float2*)(x + node0);
            float dv0 = rsqrtf((float)a + 1.0f);
            float dv1 = rsqrtf((float)c + 1.0f);
            float xd0 = xv.x * dv0, xd1 = xv.y * dv1;
            H8 o0, o1;
            o0.h2[0] = __floats2half2_rn(xd0 * w0.x, xd0 * w0.y);
            o0.h2[1] = __floats2half2_rn(xd0 * w0.z, xd0 * w0.w);
            o0.h2[2] = __floats2half2_rn(xd0 * w1.x, xd0 * w1.y);
            o0.h2[3] = __floats2half2_rn(xd0 * w1.z, xd0 * w1.w);
            o1.h2[0] = __floats2half2_rn(xd1 * w0.x, xd1 * w0.y);
            o1.h2[1] = __floats2half2_rn(xd1 * w0.z, xd1 * w0.w);
            o1.h2[2] = __floats2half2_rn(xd1 * w1.x, xd1 * w1.y);
            o1.h2[3] = __floats2half2_rn(xd1 * w1.z, xd1 * w1.w);
            ((uv4*)hs)[node0]     = o0.u;
            ((uv4*)hs)[node0 + 1] = o1.u;
        } else {
            if (node0 <= n)     rowptr[node0]     = PbQb + pex;
            if (node0 + 1 <= n) rowptr[node0 + 1] = PbQb + pex + a;
            if (node0 < n) {
                float dv = rsqrtf((float)a + 1.0f);
                float xd = x[node0] * dv;
                H8 o;
                o.h2[0] = __floats2half2_rn(xd * w0.x, xd * w0.y);
                o.h2[1] = __floats2half2_rn(xd * w0.z, xd * w0.w);
                o.h2[2] = __floats2half2_rn(xd * w1.x, xd * w1.y);
                o.h2[3] = __floats2half2_rn(xd * w1.z, xd * w1.w);
                ((uv4*)hs)[node0] = o.u;
            }
        }
    }
    __syncthreads();                        // prefixes finalized before cursor use
    // pass 2: fill own quarter into LDS stage at final offsets (L2/L3-warm re-read)
    for (int k = e0 + t * 4; k < e1; k += BTPB * 4) {
        if (k + 3 < e1) {
            uv4 p4 = *(const uv4*)(bdata + k);
#pragma unroll
            for (int z = 0; z < 4; ++z) {
                int j = (int)(p4[z] >> 20);
                if ((j >> 10) == q) {
                    int pos = atomicAdd(&off[j & 1023], 1);
                    stg[pos] = p4[z] & 0xFFFFFu;
                }
            }
        } else {
            for (int kk = k; kk < e1; ++kk) {
                unsigned p = bdata[kk];
                int j = (int)(p >> 20);
                if ((j >> 10) == q) {
                    int pos = atomicAdd(&off[j & 1023], 1);
                    stg[pos] = p & 0xFFFFFu;
                }
            }
        }
    }
    __syncthreads();
    // burst flush: contiguous, full lines
    int tot = sTot;
    for (int k = t; k < tot; k += BTPB)
        col[PbQb + k] = (int)stg[k];
}

// ---------------- seed: mark idx nodes (tag 1) + enqueue unique ----------------
__global__ void seed_mark_q(const int* __restrict__ idx, int B, int* __restrict__ mark,
                            int* __restrict__ L, int* __restrict__ qq) {
    int t = threadIdx.x;
    if (t < B) {
        int u = idx[t];
        if (atomicCAS(&mark[u], 0, 1) == 0)
            L[atomicAdd(&qq[7], 1)] = u;
    }
}

// ------- frontier expansion, tag-filtered: rows with mark == tier-1 -------------
// No index-range snapshots needed: rows appended by this very kernel carry mark==tier
// and are excluded by the filter; hi (read at entry) covers all prior-tier rows.
__global__ __launch_bounds__(TPB) void expand_f(int* __restrict__ L, int* __restrict__ qq,
                                                int tier,
                                                const int* __restrict__ rowptr,
                                                const int* __restrict__ col,
                                                int* __restrict__ mark) {
    int hi = qq[7];
    int stride = gridDim.x * blockDim.x;
    for (int r = blockIdx.x * blockDim.x + threadIdx.x; r < hi; r += stride) {
        int u = L[r];
        if (mark[u] != tier - 1) continue;
        int e0 = rowptr[u], e1 = rowptr[u + 1];
        for (int k = e0; k < e1; ++k) {
            int s = col[k];
            if (mark[s] == 0 && atomicCAS(&mark[s], 0, tier) == 0)
                L[atomicAdd(&qq[7], 1)] = s;
        }
    }
}

// ---------------- fused pull + node transform over rows with mark <= tagMax ------
// dis recomputed from rowptr diff: rsqrtf(deg+1), bit-identical to stored form.
__global__ void pull_tier(const int* __restrict__ L, const int* __restrict__ qq,
                          int tagMax, const int* __restrict__ mark,
                          const int* __restrict__ rowptr, const int* __restrict__ col,
                          const __half* __restrict__ hs_in, const float* __restrict__ bias,
                          const float* __restrict__ W, __half* __restrict__ hs_out) {
    int r = blockIdx.x * blockDim.x + threadIdx.x;
    if (r >= qq[7]) return;
    int u = L[r];
    if (mark[u] > tagMax) return;
    const uv4* hv = (const uv4*)hs_in;
    H8 p; p.u = hv[u];                       // self term
    float2 a0 = __half22float2(p.h2[0]);
    float2 a1 = __half22float2(p.h2[1]);
    float2 a2 = __half22float2(p.h2[2]);
    float2 a3 = __half22float2(p.h2[3]);
    int s = rowptr[u], e = rowptr[u + 1];
    for (int k = s; k < e; ++k) {
        H8 q; q.u = hv[col[k]];
        float2 b0 = __half22float2(q.h2[0]);
        float2 b1 = __half22float2(q.h2[1]);
        float2 b2 = __half22float2(q.h2[2]);
        float2 b3 = __half22float2(q.h2[3]);
        a0.x += b0.x; a0.y += b0.y; a1.x += b1.x; a1.y += b1.y;
        a2.x += b2.x; a2.y += b2.y; a3.x += b3.x; a3.y += b3.y;
    }
    float d = rsqrtf((float)(e - s) + 1.0f);
    float t[8] = {a0.x * d, a0.y * d, a1.x * d, a1.y * d,
                  a2.x * d, a2.y * d, a3.x * d, a3.y * d};
#pragma unroll
    for (int k = 0; k < 8; ++k) {
        float v = t[k] + bias[k];
        t[k] = v > 0.0f ? v : 0.0f;
    }
    float h[8];
#pragma unroll
    for (int j = 0; j < 8; ++j) {
        float acc = 0.0f;
#pragma unroll
        for (int k = 0; k < 8; ++k) acc += t[k] * W[k * 8 + j];
        h[j] = acc * d;
    }
    H8 o;
    o.h2[0] = __floats2half2_rn(h[0], h[1]);
    o.h2[1] = __floats2half2_rn(h[2], h[3]);
    o.h2[2] = __floats2half2_rn(h[4], h[5]);
    o.h2[3] = __floats2half2_rn(h[6], h[7]);
    ((uv4*)hs_out)[u] = o.u;
}

// ---------------- final: out[t][:] = dis*(sum+self) + b4, for the idx nodes ------
__global__ void pull_final(const int* __restrict__ idx, int B,
                           const int* __restrict__ rowptr, const int* __restrict__ col,
                           const __half* __restrict__ hs_in,
                           const float* __restrict__ b4, float* __restrict__ out) {
    int t = blockIdx.x * blockDim.x + threadIdx.x;
    if (t >= B) return;
    int u = idx[t];
    const uv4* hv = (const uv4*)hs_in;
    H8 p; p.u = hv[u];
    float2 a0 = __half22float2(p.h2[0]);
    float2 a1 = __half22float2(p.h2[1]);
    float2 a2 = __half22float2(p.h2[2]);
    float2 a3 = __half22float2(p.h2[3]);
    int s = rowptr[u], e = rowptr[u + 1];
    for (int k = s; k < e; ++k) {
        H8 q; q.u = hv[col[k]];
        float2 b0 = __half22float2(q.h2[0]);
        float2 b1 = __half22float2(q.h2[1]);
        float2 b2 = __half22float2(q.h2[2]);
        float2 b3 = __half22float2(q.h2[3]);
        a0.x += b0.x; a0.y += b0.y; a1.x += b1.x; a1.y += b1.y;
        a2.x += b2.x; a2.y += b2.y; a3.x += b3.x; a3.y += b3.y;
    }
    float d = rsqrtf((float)(e - s) + 1.0f);
    float* op = out + (size_t)t * 8;
    op[0] = a0.x * d + b4[0]; op[1] = a0.y * d + b4[1];
    op[2] = a1.x * d + b4[2]; op[3] = a1.y * d + b4[3];
    op[4] = a2.x * d + b4[4]; op[5] = a2.y * d + b4[5];
    op[6] = a3.x * d + b4[6]; op[7] = a3.y * d + b4[7];
}

extern "C" void kernel_launch(void* const* d_in, const int* in_sizes, int n_in,
                              void* d_out, int out_size, void* d_ws, size_t ws_size,
                              hipStream_t stream) {
    const float* x   = (const float*)d_in[0];
    const int*   ei  = (const int*)d_in[1];
    const int*   idx = (const int*)d_in[2];
    const float* W1  = (const float*)d_in[3];
    const float* b1  = (const float*)d_in[4];
    const float* W2  = (const float*)d_in[5];
    const float* b2  = (const float*)d_in[6];
    const float* W3  = (const float*)d_in[7];
    const float* b3  = (const float*)d_in[8];
    const float* W4  = (const float*)d_in[9];
    const float* b4  = (const float*)d_in[10];

    const int n = in_sizes[0];      // 1,000,000 nodes (n <= 2^20 for packing)
    const int E = in_sizes[1] / 2;  // 10,000,000 edges
    const int B = in_sizes[2];      // 64 graphs

    const int* src = ei;
    const int* dst = ei + E;

    const int NB = (n + BNODES - 1) / BNODES;            // 245 buckets

    // workspace (int elements):
    size_t o_mark = 0;
    size_t o_rp   = o_mark + (size_t)n;                  // n+1 (+pad)
    size_t o_hsA  = o_rp   + (size_t)n + 8;
    size_t o_L    = o_hsA  + (size_t)n * 4;
    size_t o_col  = o_L    + CAP_L;
    size_t o_bd   = o_col  + (size_t)E;                  // bdata; hsB aliases its base
    size_t o_sm   = o_bd   + (size_t)NB * CAPB;

    int*      mark   = (int*)d_ws + o_mark;
    int*      rowptr = (int*)d_ws + o_rp;
    __half*   hsA    = (__half*)((int*)d_ws + o_hsA);
    int*      L      = (int*)d_ws + o_L;
    int*      col    = (int*)d_ws + o_col;
    unsigned* bdata  = (unsigned*)((int*)d_ws + o_bd);
    __half*   hsB    = (__half*)bdata;                   // bdata dead after quarter_csr
    int*      tails  = (int*)d_ws + o_sm;
    int*      P      = tails + NBK + 8;                  // NBK+1 entries
    int*      qq     = P + NBK + 8;                      // [7]=queue tail

    const int gs  = (int)(((long)E + CH - 1) / CH);      // 1628
    const int nb2 = CAP_L / TPB;                         // 1024

    // ---- init ----
    (void)hipMemsetAsync(mark, 0, (size_t)n * sizeof(int), stream);
    (void)hipMemsetAsync(qq, 0, 16 * sizeof(int), stream);
    init_tails<<<1, NBK, 0, stream>>>(tails);

    // ---- bucket partition (LDS counting sort, burst flush) ----
    scatter_sort<<<gs, STPB, 0, stream>>>(dst, src, tails, bdata, E);

    // ---- exact full CSR from quarter-buckets (980 blocks, 2/CU; fuses layer-1) ----
    bucket_prefix<<<1, NBK, 0, stream>>>(tails, P);
    quarter_csr<<<NB * 4, BTPB, 0, stream>>>(bdata, tails, P, x, W1, rowptr, hsA, col, n);

    // ---- frontier cone expansion (tag-filtered; no snapshot launches) ----
    seed_mark_q<<<1, 64, 0, stream>>>(idx, B, mark, L, qq);
    expand_f<<<64, TPB, 0, stream>>>(L, qq, 2, rowptr, col, mark);
    expand_f<<<128, TPB, 0, stream>>>(L, qq, 3, rowptr, col, mark);
    expand_f<<<256, TPB, 0, stream>>>(L, qq, 4, rowptr, col, mark);

    // ---- layers ----
    pull_tier<<<nb2, TPB, 0, stream>>>(L, qq, 4, mark, rowptr, col, hsA, b1, W2, hsB);
    pull_tier<<<nb2, TPB, 0, stream>>>(L, qq, 3, mark, rowptr, col, hsB, b2, W3, hsA);
    pull_tier<<<nb2, TPB, 0, stream>>>(L, qq, 2, mark, rowptr, col, hsA, b3, W4, hsB);
    pull_final<<<1, 64, 0, stream>>>(idx, B, rowptr, col, hsB, b4, (float*)d_out);
}

// Round 7
// 410.554 us; speedup vs baseline: 1.8299x; 1.0261x over previous
//
#include <hip/hip_runtime.h>
#include <hip/hip_fp16.h>

#define TPB 256
#define STPB 512           // threads for scatter_sort
#define BTPB 512           // threads for quarter_csr
#define NBK 256            // bucket index space (dst >> 12); 245 used
#define BNODES 4096        // nodes per bucket
#define QNODES 1024        // nodes per quarter
#define CH 6144            // edges per scatter_sort chunk (~34 KB LDS -> 4 blocks/CU)
#define CAPB 45056         // fixed bucket capacity (mean 40960 + 20 sigma)
#define QSTG 12288         // quarter LDS stage capacity (48 KB; mean 10240 + 20 sigma)
#define CAP_L 262144       // cone row cap (|marked| ~ 92K mean)

typedef unsigned int uv4 __attribute__((ext_vector_type(4)));
union H8 { uv4 u; __half2 h2[4]; };

// ------- partition edges into fixed-capacity buckets; LDS counting sort, burst flush ---
// payload: (dstLow12 << 20) | src  (exactly 32 bits; requires n <= 2^20)
// tails[] holds pure COUNTS (memset-0 init); global run base = b*CAPB + old_count.
__global__ __launch_bounds__(STPB) void scatter_sort(const int* __restrict__ dst,
                                                     const int* __restrict__ src,
                                                     int* __restrict__ tails,
                                                     unsigned* __restrict__ bdata, int nE) {
    __shared__ unsigned      stage[CH];      // 24 KB
    __shared__ unsigned char bkt[CH];        // 6 KB
    __shared__ int cnt[NBK], sstart[NBK], cur[NBK], cbase[NBK];   // 4 KB
    __shared__ int wsum[STPB / 64];
    int t = threadIdx.x;
    long base = (long)blockIdx.x * CH;
    int m = (int)(((long)nE - base < CH) ? (nE - base) : CH);
    if (t < NBK) cnt[t] = 0;
    __syncthreads();
    // pass 1: bucket count (LDS atomics only), int4 loads
    for (int k = t * 4; k < m; k += STPB * 4) {
        if (k + 3 < m) {
            int4 d4 = *(const int4*)(dst + base + k);
            atomicAdd(&cnt[d4.x >> 12], 1);
            atomicAdd(&cnt[d4.y >> 12], 1);
            atomicAdd(&cnt[d4.z >> 12], 1);
            atomicAdd(&cnt[d4.w >> 12], 1);
        } else {
            int ke = (k + 4 < m) ? (k + 4) : m;
            for (int kk = k; kk < ke; ++kk)
                atomicAdd(&cnt[dst[base + kk] >> 12], 1);
        }
    }
    __syncthreads();
    // exclusive scan of 256 counts: wave shfl-scan (4 waves) + cross-wave, 2 barriers
    int v = 0, incl = 0;
    if (t < NBK) {
        v = cnt[t]; incl = v;
#pragma unroll
        for (int o = 1; o < 64; o <<= 1) {
            int u = __shfl_up(incl, o, 64);
            if ((t & 63) >= o) incl += u;
        }
        if ((t & 63) == 63) wsum[t >> 6] = incl;
    }
    __syncthreads();
    if (t < NBK) {
        int wadd = 0;
#pragma unroll
        for (int w = 0; w < 3; ++w) wadd += (w < (t >> 6)) ? wsum[w] : 0;
        int ex = incl - v + wadd;
        sstart[t] = ex;
        cur[t] = ex;
        cbase[t] = v ? (t * CAPB + atomicAdd(&tails[t], v)) : 0;   // reserve global run
    }
    __syncthreads();
    // pass 2: place into LDS, sorted by bucket (int4 re-reads from L2/L3)
    for (int k = t * 4; k < m; k += STPB * 4) {
        if (k + 3 < m) {
            int4 d4 = *(const int4*)(dst + base + k);
            int4 s4 = *(const int4*)(src + base + k);
            { int b = d4.x >> 12; int pos = atomicAdd(&cur[b], 1);
              stage[pos] = ((unsigned)(d4.x & 4095) << 20) | (unsigned)s4.x; bkt[pos] = (unsigned char)b; }
            { int b = d4.y >> 12; int pos = atomicAdd(&cur[b], 1);
              stage[pos] = ((unsigned)(d4.y & 4095) << 20) | (unsigned)s4.y; bkt[pos] = (unsigned char)b; }
            { int b = d4.z >> 12; int pos = atomicAdd(&cur[b], 1);
              stage[pos] = ((unsigned)(d4.z & 4095) << 20) | (unsigned)s4.z; bkt[pos] = (unsigned char)b; }
            { int b = d4.w >> 12; int pos = atomicAdd(&cur[b], 1);
              stage[pos] = ((unsigned)(d4.w & 4095) << 20) | (unsigned)s4.w; bkt[pos] = (unsigned char)b; }
        } else {
            int ke = (k + 4 < m) ? (k + 4) : m;
            for (int kk = k; kk < ke; ++kk) {
                int d = dst[base + kk], s = src[base + kk];
                int b = d >> 12; int pos = atomicAdd(&cur[b], 1);
                stage[pos] = ((unsigned)(d & 4095) << 20) | (unsigned)s; bkt[pos] = (unsigned char)b;
            }
        }
    }
    __syncthreads();
    // burst flush: consecutive threads -> consecutive dests within runs
    for (int k = t; k < m; k += STPB) {
        int b = bkt[k];
        bdata[cbase[b] + (k - sstart[b])] = stage[k];
    }
}

// ------- per-QUARTER exact CSR build, XCD-swizzled (4 quarters of a bucket -> same XCD) -
// bid -> (xcd = bid&7, slot = bid>>3); bucket = (slot>>2)*8 + xcd; q = slot&3.
// Assuming HW round-robin bid->XCD, a bucket's 4 blocks share one L2 and run adjacently,
// so its 180 KB of bdata stays L2-resident across all 8 scan passes.
// Computes its own Pb (sum of earlier buckets' counts) -- bucket_prefix kernel removed.
// LDS-staged burst flush; fuses layer-1: hs[node] = pack(x[node]*dis*W1row).
__global__ __launch_bounds__(BTPB) void quarter_csr(const unsigned* __restrict__ bdata,
                                                    const int* __restrict__ tails,
                                                    const float* __restrict__ x,
                                                    const float* __restrict__ W1,
                                                    int* __restrict__ rowptr,
                                                    __half* __restrict__ hs,
                                                    int* __restrict__ col, int n, int NB) {
    __shared__ int      off[QNODES];       // 4 KB (counts -> prefix -> cursor)
    __shared__ int      wsum[BTPB / 64];   // scan wave partials
    __shared__ int      wredQ[BTPB / 64];  // Qb reduction partials
    __shared__ int      wredP[BTPB / 64];  // Pb reduction partials
    __shared__ int      sQb, sTot, sPb;
    __shared__ unsigned stg[QSTG];         // 48 KB
    int bid = blockIdx.x, t = threadIdx.x;
    int xcd = bid & 7, slot = bid >> 3;
    int b = (slot >> 2) * 8 + xcd;
    int q = slot & 3;
    if (b >= NB) return;                   // uniform per block
    int e0 = b * CAPB, e1 = e0 + tails[b];
    for (int j = t; j < QNODES; j += BTPB) off[j] = 0;
    // Pb = sum of counts of buckets < b (4-wave reduce over tails[0..b))
    int partial = (t < b) ? tails[t] : 0;
#pragma unroll
    for (int o = 32; o > 0; o >>= 1) partial += __shfl_down(partial, o, 64);
    if ((t & 63) == 0) wredP[t >> 6] = partial;
    __syncthreads();                        // (1) off zeroed, wredP ready
    if (t == 0) {
        int s = 0;
#pragma unroll
        for (int w = 0; w < BTPB / 64; ++w) s += wredP[w];
        sPb = s;
    }
    // pass 1: count own quarter's degrees + tally edges of earlier quarters (Qb)
    int before = 0;
    for (int k = e0 + t * 4; k < e1; k += BTPB * 4) {
        if (k + 3 < e1) {
            uv4 p4 = *(const uv4*)(bdata + k);
#pragma unroll
            for (int z = 0; z < 4; ++z) {
                int j = (int)(p4[z] >> 20); int jq = j >> 10;
                if (jq == q) atomicAdd(&off[j & 1023], 1);
                before += (jq < q) ? 1 : 0;
            }
        } else {
            for (int kk = k; kk < e1; ++kk) {
                int j = (int)(bdata[kk] >> 20); int jq = j >> 10;
                if (jq == q) atomicAdd(&off[j & 1023], 1);
                before += (jq < q) ? 1 : 0;
            }
        }
    }
#pragma unroll
    for (int o = 32; o > 0; o >>= 1) before += __shfl_down(before, o, 64);
    if ((t & 63) == 0) wredQ[t >> 6] = before;
    __syncthreads();                        // (2) counts + wredQ + sPb ready
    if (t == 0) {
        int s = 0;
#pragma unroll
        for (int w = 0; w < BTPB / 64; ++w) s += wredQ[w];
        sQb = s;
    }
    // scan 1024 counts: thread t owns off[2t], off[2t+1]
    int a = off[2 * t], c = off[2 * t + 1];
    int s2 = a + c;
    int incl = s2;
#pragma unroll
    for (int o = 1; o < 64; o <<= 1) {
        int u = __shfl_up(incl, o, 64);
        if ((t & 63) >= o) incl += u;
    }
    if ((t & 63) == 63) wsum[t >> 6] = incl;
    __syncthreads();                        // (3) wsum + sQb visible
    int wadd = 0;
#pragma unroll
    for (int w = 0; w < BTPB / 64 - 1; ++w) wadd += (w < (t >> 6)) ? wsum[w] : 0;
    int pex = incl - s2 + wadd;
    off[2 * t]     = pex;
    off[2 * t + 1] = pex + a;
    if (t == BTPB - 1) sTot = pex + s2;     // quarter's total edge count
    int PbQb = sPb + sQb;
    // fused rowptr + layer-1 for own 2 nodes (deg = a, c; all in registers)
    {
        int node0 = (b << 12) + (q << 10) + 2 * t;
        float4 w0 = ((const float4*)W1)[0];
        float4 w1 = ((const float4*)W1)[1];
        if (node0 + 1 < n) {
            int2 rp; rp.x = PbQb + pex; rp.y = PbQb + pex + a;
            *(int2*)(rowptr + node0) = rp;
            float2 xv = *(const float2*)(x + node0);
            float dv0 = rsqrtf((float)a + 1.0f);
            float dv1 = rsqrtf((float)c + 1.0f);
            float xd0 = xv.x * dv0, xd1 = xv.y * dv1;
            H8 o0, o1;
            o0.h2[0] = __floats2half2_rn(xd0 * w0.x, xd0 * w0.y);
            o0.h2[1] = __floats2half2_rn(xd0 * w0.z, xd0 * w0.w);
            o0.h2[2] = __floats2half2_rn(xd0 * w1.x, xd0 * w1.y);
            o0.h2[3] = __floats2half2_rn(xd0 * w1.z, xd0 * w1.w);
            o1.h2[0] = __floats2half2_rn(xd1 * w0.x, xd1 * w0.y);
            o1.h2[1] = __floats2half2_rn(xd1 * w0.z, xd1 * w0.w);
            o1.h2[2] = __floats2half2_rn(xd1 * w1.x, xd1 * w1.y);
            o1.h2[3] = __floats2half2_rn(xd1 * w1.z, xd1 * w1.w);
            ((uv4*)hs)[node0]     = o0.u;
            ((uv4*)hs)[node0 + 1] = o1.u;
        } else {
            if (node0 <= n)     rowptr[node0]     = PbQb + pex;
            if (node0 + 1 <= n) rowptr[node0 + 1] = PbQb + pex + a;
            if (node0 < n) {
                float dv = rsqrtf((float)a + 1.0f);
                float xd = x[node0] * dv;
                H8 o;
                o.h2[0] = __floats2half2_rn(xd * w0.x, xd * w0.y);
                o.h2[1] = __floats2half2_rn(xd * w0.z, xd * w0.w);
                o.h2[2] = __floats2half2_rn(xd * w1.x, xd * w1.y);
                o.h2[3] = __floats2half2_rn(xd * w1.z, xd * w1.w);
                ((uv4*)hs)[node0] = o.u;
            }
        }
    }
    __syncthreads();                        // (4) prefixes finalized before cursor use
    // pass 2: fill own quarter into LDS stage at final offsets (L2-warm re-read)
    for (int k = e0 + t * 4; k < e1; k += BTPB * 4) {
        if (k + 3 < e1) {
            uv4 p4 = *(const uv4*)(bdata + k);
#pragma unroll
            for (int z = 0; z < 4; ++z) {
                int j = (int)(p4[z] >> 20);
                if ((j >> 10) == q) {
                    int pos = atomicAdd(&off[j & 1023], 1);
                    stg[pos] = p4[z] & 0xFFFFFu;
                }
            }
        } else {
            for (int kk = k; kk < e1; ++kk) {
                unsigned p = bdata[kk];
                int j = (int)(p >> 20);
                if ((j >> 10) == q) {
                    int pos = atomicAdd(&off[j & 1023], 1);
                    stg[pos] = p & 0xFFFFFu;
                }
            }
        }
    }
    __syncthreads();                        // (5)
    // burst flush: contiguous, full lines
    int tot = sTot;
    for (int k = t; k < tot; k += BTPB)
        col[PbQb + k] = (int)stg[k];
}

// ---------------- seed: mark idx nodes (tag 1) + enqueue unique ----------------
__global__ void seed_mark_q(const int* __restrict__ idx, int B, int* __restrict__ mark,
                            int* __restrict__ L, int* __restrict__ qq) {
    int t = threadIdx.x;
    if (t < B) {
        int u = idx[t];
        if (atomicCAS(&mark[u], 0, 1) == 0)
            L[atomicAdd(&qq[7], 1)] = u;
    }
}

// ------- frontier expansion, tag-filtered, wave-aggregated enqueue -------------
// One atomicAdd(&qq[7]) per wave-iteration instead of per edge (same-address global
// atomics serialize at L2); L appends become wave-coalesced.
__global__ __launch_bounds__(TPB) void expand_f(int* __restrict__ L, int* __restrict__ qq,
                                                int tier,
                                                const int* __restrict__ rowptr,
                                                const int* __restrict__ col,
                                                int* __restrict__ mark) {
    int hi = qq[7];
    int stride = gridDim.x * blockDim.x;
    int lane = threadIdx.x & 63;
    for (int r = blockIdx.x * blockDim.x + threadIdx.x; r < hi; r += stride) {
        int u = L[r];
        if (mark[u] != tier - 1) continue;
        int e0 = rowptr[u], e1 = rowptr[u + 1];
        for (int k = e0; k < e1; ++k) {
            int s = col[k];
            bool ok = (mark[s] == 0) && (atomicCAS(&mark[s], 0, tier) == 0);
            unsigned long long msk = __ballot(ok);
            if (msk) {
                int leader = __builtin_ctzll(msk);
                int cntw = __builtin_popcountll(msk);
                int basep = 0;
                if (lane == leader) basep = atomicAdd(&qq[7], cntw);
                basep = __shfl(basep, leader, 64);
                if (ok) {
                    int myoff = __builtin_popcountll(msk & ((1ull << lane) - 1ull));
                    L[basep + myoff] = s;
                }
            }
        }
    }
}

// ---------------- fused pull + node transform over rows with mark <= tagMax ------
// dis recomputed from rowptr diff: rsqrtf(deg+1), bit-identical to stored form.
__global__ void pull_tier(const int* __restrict__ L, const int* __restrict__ qq,
                          int tagMax, const int* __restrict__ mark,
                          const int* __restrict__ rowptr, const int* __restrict__ col,
                          const __half* __restrict__ hs_in, const float* __restrict__ bias,
                          const float* __restrict__ W, __half* __restrict__ hs_out) {
    int r = blockIdx.x * blockDim.x + threadIdx.x;
    if (r >= qq[7]) return;
    int u = L[r];
    if (mark[u] > tagMax) return;
    const uv4* hv = (const uv4*)hs_in;
    H8 p; p.u = hv[u];                       // self term
    float2 a0 = __half22float2(p.h2[0]);
    float2 a1 = __half22float2(p.h2[1]);
    float2 a2 = __half22float2(p.h2[2]);
    float2 a3 = __half22float2(p.h2[3]);
    int s = rowptr[u], e = rowptr[u + 1];
    for (int k = s; k < e; ++k) {
        H8 q; q.u = hv[col[k]];
        float2 b0 = __half22float2(q.h2[0]);
        float2 b1 = __half22float2(q.h2[1]);
        float2 b2 = __half22float2(q.h2[2]);
        float2 b3 = __half22float2(q.h2[3]);
        a0.x += b0.x; a0.y += b0.y; a1.x += b1.x; a1.y += b1.y;
        a2.x += b2.x; a2.y += b2.y; a3.x += b3.x; a3.y += b3.y;
    }
    float d = rsqrtf((float)(e - s) + 1.0f);
    float t[8] = {a0.x * d, a0.y * d, a1.x * d, a1.y * d,
                  a2.x * d, a2.y * d, a3.x * d, a3.y * d};
#pragma unroll
    for (int k = 0; k < 8; ++k) {
        float v = t[k] + bias[k];
        t[k] = v > 0.0f ? v : 0.0f;
    }
    float h[8];
#pragma unroll
    for (int j = 0; j < 8; ++j) {
        float acc = 0.0f;
#pragma unroll
        for (int k = 0; k < 8; ++k) acc += t[k] * W[k * 8 + j];
        h[j] = acc * d;
    }
    H8 o;
    o.h2[0] = __floats2half2_rn(h[0], h[1]);
    o.h2[1] = __floats2half2_rn(h[2], h[3]);
    o.h2[2] = __floats2half2_rn(h[4], h[5]);
    o.h2[3] = __floats2half2_rn(h[6], h[7]);
    ((uv4*)hs_out)[u] = o.u;
}

// ---------------- final: out[t][:] = dis*(sum+self) + b4, for the idx nodes ------
__global__ void pull_final(const int* __restrict__ idx, int B,
                           const int* __restrict__ rowptr, const int* __restrict__ col,
                           const __half* __restrict__ hs_in,
                           const float* __restrict__ b4, float* __restrict__ out) {
    int t = blockIdx.x * blockDim.x + threadIdx.x;
    if (t >= B) return;
    int u = idx[t];
    const uv4* hv = (const uv4*)hs_in;
    H8 p; p.u = hv[u];
    float2 a0 = __half22float2(p.h2[0]);
    float2 a1 = __half22float2(p.h2[1]);
    float2 a2 = __half22float2(p.h2[2]);
    float2 a3 = __half22float2(p.h2[3]);
    int s = rowptr[u], e = rowptr[u + 1];
    for (int k = s; k < e; ++k) {
        H8 q; q.u = hv[col[k]];
        float2 b0 = __half22float2(q.h2[0]);
        float2 b1 = __half22float2(q.h2[1]);
        float2 b2 = __half22float2(q.h2[2]);
        float2 b3 = __half22float2(q.h2[3]);
        a0.x += b0.x; a0.y += b0.y; a1.x += b1.x; a1.y += b1.y;
        a2.x += b2.x; a2.y += b2.y; a3.x += b3.x; a3.y += b3.y;
    }
    float d = rsqrtf((float)(e - s) + 1.0f);
    float* op = out + (size_t)t * 8;
    op[0] = a0.x * d + b4[0]; op[1] = a0.y * d + b4[1];
    op[2] = a1.x * d + b4[2]; op[3] = a1.y * d + b4[3];
    op[4] = a2.x * d + b4[4]; op[5] = a2.y * d + b4[5];
    op[6] = a3.x * d + b4[6]; op[7] = a3.y * d + b4[7];
}

extern "C" void kernel_launch(void* const* d_in, const int* in_sizes, int n_in,
                              void* d_out, int out_size, void* d_ws, size_t ws_size,
                              hipStream_t stream) {
    const float* x   = (const float*)d_in[0];
    const int*   ei  = (const int*)d_in[1];
    const int*   idx = (const int*)d_in[2];
    const float* W1  = (const float*)d_in[3];
    const float* b1  = (const float*)d_in[4];
    const float* W2  = (const float*)d_in[5];
    const float* b2  = (const float*)d_in[6];
    const float* W3  = (const float*)d_in[7];
    const float* b3  = (const float*)d_in[8];
    const float* W4  = (const float*)d_in[9];
    const float* b4  = (const float*)d_in[10];

    const int n = in_sizes[0];      // 1,000,000 nodes (n <= 2^20 for packing)
    const int E = in_sizes[1] / 2;  // 10,000,000 edges
    const int B = in_sizes[2];      // 64 graphs

    const int* src = ei;
    const int* dst = ei + E;

    const int NB = (n + BNODES - 1) / BNODES;            // 245 buckets

    // workspace (int elements):
    size_t o_mark = 0;
    size_t o_rp   = o_mark + (size_t)n;                  // n+1 (+pad)
    size_t o_hsA  = o_rp   + (size_t)n + 8;
    size_t o_L    = o_hsA  + (size_t)n * 4;
    size_t o_col  = o_L    + CAP_L;
    size_t o_bd   = o_col  + (size_t)E;                  // bdata; hsB aliases its base
    size_t o_sm   = o_bd   + (size_t)NB * CAPB;

    int*      mark   = (int*)d_ws + o_mark;
    int*      rowptr = (int*)d_ws + o_rp;
    __half*   hsA    = (__half*)((int*)d_ws + o_hsA);
    int*      L      = (int*)d_ws + o_L;
    int*      col    = (int*)d_ws + o_col;
    unsigned* bdata  = (unsigned*)((int*)d_ws + o_bd);
    __half*   hsB    = (__half*)bdata;                   // bdata dead after quarter_csr
    int*      tails  = (int*)d_ws + o_sm;                // NBK counts
    int*      qq     = tails + NBK;                      // [7]=queue tail (contiguous)

    const int gs  = (int)(((long)E + CH - 1) / CH);      // 1628
    const int nb2 = CAP_L / TPB;                         // 1024
    const int gq  = ((NB + 7) / 8) * 32;                 // 992 swizzled quarter blocks

    // ---- init (tails+qq contiguous -> one small memset) ----
    (void)hipMemsetAsync(mark, 0, (size_t)n * sizeof(int), stream);
    (void)hipMemsetAsync(tails, 0, (NBK + 16) * sizeof(int), stream);

    // ---- bucket partition (LDS counting sort, burst flush) ----
    scatter_sort<<<gs, STPB, 0, stream>>>(dst, src, tails, bdata, E);

    // ---- exact full CSR from XCD-swizzled quarter-buckets (fuses Pb + layer-1) ----
    quarter_csr<<<gq, BTPB, 0, stream>>>(bdata, tails, x, W1, rowptr, hsA, col, n, NB);

    // ---- frontier cone expansion (tag-filtered; wave-aggregated enqueue) ----
    seed_mark_q<<<1, 64, 0, stream>>>(idx, B, mark, L, qq);
    expand_f<<<64, TPB, 0, stream>>>(L, qq, 2, rowptr, col, mark);
    expand_f<<<128, TPB, 0, stream>>>(L, qq, 3, rowptr, col, mark);
    expand_f<<<256, TPB, 0, stream>>>(L, qq, 4, rowptr, col, mark);

    // ---- layers ----
    pull_tier<<<nb2, TPB, 0, stream>>>(L, qq, 4, mark, rowptr, col, hsA, b1, W2, hsB);
    pull_tier<<<nb2, TPB, 0, stream>>>(L, qq, 3, mark, rowptr, col, hsB, b2, W3, hsA);
    pull_tier<<<nb2, TPB, 0, stream>>>(L, qq, 2, mark, rowptr, col, hsA, b3, W4, hsB);
    pull_final<<<1, 64, 0, stream>>>(idx, B, rowptr, col, hsB, b4, (float*)d_out);
}